// Round 1
// baseline (208.282 us; speedup 1.0000x reference)
//
#include <hip/hip_runtime.h>

// Linear attention (non-causal), N=4, L=8192, H=16, D=M=64, fp32.
//   fm(x) = elu(x)+1 = (x>0 ? x+1 : exp(x))
//   KV[n,h,d,m] = sum_s fm(K[n,s,h,d]) * V[n,s,h,m]
//   Ksum[n,h,d] = sum_s fm(K[n,s,h,d])
//   z[n,l,h]    = 1/(fm(Q[n,l,h,:]) . Ksum[n,h,:]) + 1e-10
//   out[n,l,h,m]= z * sum_d fm(Q[n,l,h,d]) * KV[n,h,d,m]
//
// Memory-bound: 512 MiB total traffic -> ~81us floor at 6.3 TB/s.
// fp32 VALU compute (8.6 GF ~ 55us) hides under memory. No MFMA (no fp32 MFMA on CDNA4).

#define EPSV      1e-10f
#define L_SEQ     8192
#define H_HEADS   16
#define D_DIM     64
#define NH_TOT    64          // N*H
#define ROWSTRIDE 1024        // H*D, stride (in floats) between consecutive l/s
#define KV_STRIDE 4160        // per-(n,h) ws row: 4096 KV + 64 Ksum
#define QSTRIDE   68          // padded LDS stride for Q tile (bank-conflict-free)

__device__ __forceinline__ float fm(float x) {
    return x > 0.0f ? x + 1.0f : __expf(x);
}

// ---------------- Pass 1: KV + Ksum reduction over s ----------------
// grid: (64 nh, 16 chunks of 512 s-rows), block: 256
__global__ __launch_bounds__(256) void kv_reduce_kernel(
    const float* __restrict__ K, const float* __restrict__ V,
    float* __restrict__ KVg)
{
    const int t     = threadIdx.x;
    const int nh    = blockIdx.x;        // 0..63
    const int chunk = blockIdx.y;        // 0..15
    const int n  = nh >> 4, h = nh & 15;

    const int rg = t >> 4;               // staging row group 0..15
    const int dq = (t & 15) << 2;        // staging column quad (also thread's ksum slice)
    const int d0 = (t >> 4) << 2;        // compute tile row base (d)
    const int m0 = (t & 15) << 2;        // compute tile col base (m)

    __shared__ float Kl[32 * 64];
    __shared__ float Vl[32 * 64];
    __shared__ float ksp[16 * 64];

    float acc[4][4] = {};
    float ks[4] = {0.f, 0.f, 0.f, 0.f};

    const int base = n * (L_SEQ * ROWSTRIDE) + h * D_DIM;
    int s0 = chunk * 512;

    for (int tile = 0; tile < 16; ++tile, s0 += 32) {
        // stage 32 rows of K (feature-mapped) and V into LDS
#pragma unroll
        for (int p = 0; p < 2; ++p) {
            const int rr = p * 16 + rg;
            const int ga = base + (s0 + rr) * ROWSTRIDE + dq;
            const float4 kg = *reinterpret_cast<const float4*>(K + ga);
            const float4 vg = *reinterpret_cast<const float4*>(V + ga);
            float4 kf;
            kf.x = fm(kg.x); kf.y = fm(kg.y); kf.z = fm(kg.z); kf.w = fm(kg.w);
            ks[0] += kf.x; ks[1] += kf.y; ks[2] += kf.z; ks[3] += kf.w;
            *reinterpret_cast<float4*>(&Kl[rr * 64 + dq]) = kf;
            *reinterpret_cast<float4*>(&Vl[rr * 64 + dq]) = vg;
        }
        __syncthreads();
#pragma unroll 8
        for (int s = 0; s < 32; ++s) {
            const float4 k4 = *reinterpret_cast<const float4*>(&Kl[s * 64 + d0]);
            const float4 v4 = *reinterpret_cast<const float4*>(&Vl[s * 64 + m0]);
            acc[0][0] += k4.x * v4.x; acc[0][1] += k4.x * v4.y; acc[0][2] += k4.x * v4.z; acc[0][3] += k4.x * v4.w;
            acc[1][0] += k4.y * v4.x; acc[1][1] += k4.y * v4.y; acc[1][2] += k4.y * v4.z; acc[1][3] += k4.y * v4.w;
            acc[2][0] += k4.z * v4.x; acc[2][1] += k4.z * v4.y; acc[2][2] += k4.z * v4.z; acc[2][3] += k4.z * v4.w;
            acc[3][0] += k4.w * v4.x; acc[3][1] += k4.w * v4.y; acc[3][2] += k4.w * v4.z; acc[3][3] += k4.w * v4.w;
        }
        __syncthreads();
    }

    // reduce ksum partials across the 16 row-groups
    *reinterpret_cast<float4*>(&ksp[rg * 64 + dq]) = *reinterpret_cast<float4*>(ks);
    __syncthreads();

    float* kvrow = KVg + nh * KV_STRIDE;
    if (t < 64) {
        float ssum = 0.f;
#pragma unroll
        for (int g = 0; g < 16; ++g) ssum += ksp[g * 64 + t];
        atomicAdd(kvrow + 4096 + t, ssum);
    }
#pragma unroll
    for (int i = 0; i < 4; ++i) {
#pragma unroll
        for (int j = 0; j < 4; ++j) {
            atomicAdd(kvrow + (d0 + i) * 64 + (m0 + j), acc[i][j]);
        }
    }
}

// ---------------- Pass 2: out = z * (fm(Q) @ KV) ----------------
// grid: (128 l-chunks of 64 rows, 64 nh), block: 256
__global__ __launch_bounds__(256) void out_kernel(
    const float* __restrict__ Q, const float* __restrict__ KVg,
    float* __restrict__ out)
{
    const int t      = threadIdx.x;
    const int lchunk = blockIdx.x;       // 0..127
    const int nh     = blockIdx.y;       // 0..63
    const int n = nh >> 4, h = nh & 15;

    __shared__ float Ql[64 * QSTRIDE];
    __shared__ float KVl[4096];
    __shared__ float Ks[64];
    __shared__ float zl[64];

    const float* kvrow = KVg + nh * KV_STRIDE;

    // phase A: stage KV (16KB) + Ksum into LDS (KV rows are L2-resident re-reads)
#pragma unroll
    for (int j = 0; j < 4; ++j) {
        reinterpret_cast<float4*>(KVl)[t + 256 * j] =
            reinterpret_cast<const float4*>(kvrow)[t + 256 * j];
    }
    if (t < 16) {
        reinterpret_cast<float4*>(Ks)[t] =
            reinterpret_cast<const float4*>(kvrow + 4096)[t];
    }
    __syncthreads();

    // phase B: stage 64 Q rows (feature-mapped) + compute z per row
    const int lane16 = t & 15, grp = t >> 4;
    const int dq = lane16 << 2;
    const float4 ks4 = *reinterpret_cast<const float4*>(&Ks[dq]);
    const int qbase = (n * L_SEQ + lchunk * 64) * ROWSTRIDE + h * D_DIM;
#pragma unroll
    for (int p = 0; p < 4; ++p) {
        const int rr = p * 16 + grp;
        const float4 qg = *reinterpret_cast<const float4*>(Q + qbase + rr * ROWSTRIDE + dq);
        float4 qf;
        qf.x = fm(qg.x); qf.y = fm(qg.y); qf.z = fm(qg.z); qf.w = fm(qg.w);
        *reinterpret_cast<float4*>(&Ql[rr * QSTRIDE + dq]) = qf;
        float dp = qf.x * ks4.x + qf.y * ks4.y + qf.z * ks4.z + qf.w * ks4.w;
        dp += __shfl_xor(dp, 1);
        dp += __shfl_xor(dp, 2);
        dp += __shfl_xor(dp, 4);
        dp += __shfl_xor(dp, 8);
        if (lane16 == 0) zl[rr] = 1.0f / dp + EPSV;
    }
    __syncthreads();

    // phase C: 64x64x64 register-tiled GEMM, 4x4 tile per thread
    const int r0 = grp << 2;
    const int c0 = lane16 << 2;
    float acc[4][4] = {};
#pragma unroll 2
    for (int d = 0; d < 64; d += 4) {
        const float4 b0 = *reinterpret_cast<const float4*>(&KVl[(d + 0) * 64 + c0]);
        const float4 b1 = *reinterpret_cast<const float4*>(&KVl[(d + 1) * 64 + c0]);
        const float4 b2 = *reinterpret_cast<const float4*>(&KVl[(d + 2) * 64 + c0]);
        const float4 b3 = *reinterpret_cast<const float4*>(&KVl[(d + 3) * 64 + c0]);
#define DO_ROW(i) do {                                                              \
        const float4 q = *reinterpret_cast<const float4*>(&Ql[(r0 + (i)) * QSTRIDE + d]); \
        acc[i][0] += q.x * b0.x + q.y * b1.x + q.z * b2.x + q.w * b3.x;             \
        acc[i][1] += q.x * b0.y + q.y * b1.y + q.z * b2.y + q.w * b3.y;             \
        acc[i][2] += q.x * b0.z + q.y * b1.z + q.z * b2.z + q.w * b3.z;             \
        acc[i][3] += q.x * b0.w + q.y * b1.w + q.z * b2.w + q.w * b3.w;             \
    } while (0)
        DO_ROW(0); DO_ROW(1); DO_ROW(2); DO_ROW(3);
#undef DO_ROW
    }

    // epilogue: scale by z, coalesced float4 stores
    const int obase = qbase;  // out has identical [N,L,H,64] layout
#pragma unroll
    for (int i = 0; i < 4; ++i) {
        const float z = zl[r0 + i];
        float4 o;
        o.x = acc[i][0] * z; o.y = acc[i][1] * z; o.z = acc[i][2] * z; o.w = acc[i][3] * z;
        *reinterpret_cast<float4*>(out + obase + (r0 + i) * ROWSTRIDE + c0) = o;
    }
}

extern "C" void kernel_launch(void* const* d_in, const int* in_sizes, int n_in,
                              void* d_out, int out_size, void* d_ws, size_t ws_size,
                              hipStream_t stream) {
    const float* Q = (const float*)d_in[0];
    const float* K = (const float*)d_in[1];
    const float* V = (const float*)d_in[2];
    float* out = (float*)d_out;
    float* KVg = (float*)d_ws;   // 64 * 4160 floats = 1.06 MB

    hipMemsetAsync(d_ws, 0, NH_TOT * KV_STRIDE * sizeof(float), stream);
    kv_reduce_kernel<<<dim3(NH_TOT, 16), 256, 0, stream>>>(K, V, KVg);
    out_kernel<<<dim3(L_SEQ / 64, NH_TOT), 256, 0, stream>>>(Q, KVg, out);
}

// Round 2
// 187.320 us; speedup vs baseline: 1.1119x; 1.1119x over previous
//
#include <hip/hip_runtime.h>

// Linear attention (non-causal), N=4, L=8192, H=16, D=M=64, fp32.
//   fm(x) = elu(x)+1
//   KV[n,h,d,m] = sum_s fm(K[n,s,h,d]) * V[n,s,h,m]
//   Ksum[n,h,d] = sum_s fm(K[n,s,h,d])
//   z[n,l,h]    = 1/(fm(Q[n,l,h,:]) . Ksum[n,h,:]) + 1e-10
//   out[n,l,h,m]= z * sum_d fm(Q[n,l,h,d]) * KV[n,h,d,m]
//
// R1 post-mortem: pass1 was latency-bound (VALUBusy 27%, HBM 11%, occ 34%).
// R2: register-prefetch pipeline in pass1 + split-K partials (no atomics) +
// LDS 20->16KB. Pass2 unchanged.

#define EPSV      1e-10f
#define L_SEQ     8192
#define NH_TOT    64          // N*H
#define ROWSTRIDE 1024        // H*D floats between consecutive s/l
#define KV_STRIDE 4160        // per-(n,h): 4096 KV + 64 Ksum
#define SLICE     (NH_TOT * KV_STRIDE)   // floats per chunk-slice = 266240
#define QSTRIDE   68

__device__ __forceinline__ float fm(float x) {
    return x > 0.0f ? x + 1.0f : __expf(x);
}

// ---------------- Pass 1: KV + Ksum partial reduction over s ----------------
// grid: (64 nh, CH chunks), block 256. mode=1: store partials to ws[chunk][nh];
// mode=0: atomicAdd into ws[nh] (fallback, ws pre-zeroed).
__global__ __launch_bounds__(256) void kv_reduce_kernel(
    const float* __restrict__ K, const float* __restrict__ V,
    float* __restrict__ ws, int tiles, int mode)
{
    const int t     = threadIdx.x;
    const int nh    = blockIdx.x;
    const int chunk = blockIdx.y;
    const int n  = nh >> 4, h = nh & 15;

    const int rg = t >> 4;               // staging row group 0..15
    const int dq = (t & 15) << 2;        // staging column quad
    const int d0 = (t >> 4) << 2;        // compute tile row base (d)
    const int m0 = (t & 15) << 2;        // compute tile col base (m)

    __shared__ float Kl[32 * 64];
    __shared__ float Vl[32 * 64];

    float acc[4][4] = {};
    float ks[4] = {0.f, 0.f, 0.f, 0.f};

    const int base = n * (L_SEQ * ROWSTRIDE) + h * 64;
    const int s0   = chunk * (tiles * 32);

    // prologue: prefetch tile 0 into registers
    float4 kr0, kr1, vr0, vr1;
    {
        const int ga0 = base + (s0 + rg) * ROWSTRIDE + dq;
        const int ga1 = ga0 + 16 * ROWSTRIDE;
        kr0 = *reinterpret_cast<const float4*>(K + ga0);
        kr1 = *reinterpret_cast<const float4*>(K + ga1);
        vr0 = *reinterpret_cast<const float4*>(V + ga0);
        vr1 = *reinterpret_cast<const float4*>(V + ga1);
    }

    for (int tile = 0; tile < tiles; ++tile) {
        // (a) transform + store current tile regs -> LDS
        float4 kf0, kf1;
        kf0.x = fm(kr0.x); kf0.y = fm(kr0.y); kf0.z = fm(kr0.z); kf0.w = fm(kr0.w);
        kf1.x = fm(kr1.x); kf1.y = fm(kr1.y); kf1.z = fm(kr1.z); kf1.w = fm(kr1.w);
        ks[0] += kf0.x + kf1.x; ks[1] += kf0.y + kf1.y;
        ks[2] += kf0.z + kf1.z; ks[3] += kf0.w + kf1.w;
        *reinterpret_cast<float4*>(&Kl[rg * 64 + dq])        = kf0;
        *reinterpret_cast<float4*>(&Kl[(rg + 16) * 64 + dq]) = kf1;
        *reinterpret_cast<float4*>(&Vl[rg * 64 + dq])        = vr0;
        *reinterpret_cast<float4*>(&Vl[(rg + 16) * 64 + dq]) = vr1;
        __syncthreads();

        // (c) issue next tile's global loads; they land during compute below
        if (tile + 1 < tiles) {
            const int ga0 = base + (s0 + (tile + 1) * 32 + rg) * ROWSTRIDE + dq;
            const int ga1 = ga0 + 16 * ROWSTRIDE;
            kr0 = *reinterpret_cast<const float4*>(K + ga0);
            kr1 = *reinterpret_cast<const float4*>(K + ga1);
            vr0 = *reinterpret_cast<const float4*>(V + ga0);
            vr1 = *reinterpret_cast<const float4*>(V + ga1);
        }

        // (d) compute 32 rank-1 updates from LDS
#pragma unroll 8
        for (int s = 0; s < 32; ++s) {
            const float4 k4 = *reinterpret_cast<const float4*>(&Kl[s * 64 + d0]);
            const float4 v4 = *reinterpret_cast<const float4*>(&Vl[s * 64 + m0]);
            acc[0][0] += k4.x * v4.x; acc[0][1] += k4.x * v4.y; acc[0][2] += k4.x * v4.z; acc[0][3] += k4.x * v4.w;
            acc[1][0] += k4.y * v4.x; acc[1][1] += k4.y * v4.y; acc[1][2] += k4.y * v4.z; acc[1][3] += k4.y * v4.w;
            acc[2][0] += k4.z * v4.x; acc[2][1] += k4.z * v4.y; acc[2][2] += k4.z * v4.z; acc[2][3] += k4.z * v4.w;
            acc[3][0] += k4.w * v4.x; acc[3][1] += k4.w * v4.y; acc[3][2] += k4.w * v4.z; acc[3][3] += k4.w * v4.w;
        }
        __syncthreads();
    }

    // ksum partial reduce across the 16 row-groups (alias Vl, loop ended with barrier)
    float* ksp = Vl;
    *reinterpret_cast<float4*>(&ksp[rg * 64 + dq]) = *reinterpret_cast<float4*>(ks);
    __syncthreads();

    float* dst = ws + (size_t)(mode ? (chunk * NH_TOT + nh) : nh) * KV_STRIDE;

    if (mode) {
        // deterministic partial store, fully coalesced float4
#pragma unroll
        for (int i = 0; i < 4; ++i) {
            float4 o; o.x = acc[i][0]; o.y = acc[i][1]; o.z = acc[i][2]; o.w = acc[i][3];
            *reinterpret_cast<float4*>(dst + (d0 + i) * 64 + m0) = o;
        }
        if (t < 64) {
            float ssum = 0.f;
#pragma unroll
            for (int g = 0; g < 16; ++g) ssum += ksp[g * 64 + t];
            dst[4096 + t] = ssum;
        }
    } else {
        // atomic fallback (ws pre-zeroed)
#pragma unroll
        for (int i = 0; i < 4; ++i)
#pragma unroll
            for (int j = 0; j < 4; ++j)
                atomicAdd(dst + (d0 + i) * 64 + (m0 + j), acc[i][j]);
        if (t < 64) {
            float ssum = 0.f;
#pragma unroll
            for (int g = 0; g < 16; ++g) ssum += ksp[g * 64 + t];
            atomicAdd(dst + 4096 + t, ssum);
        }
    }
}

// ---------------- Reduce: sum CH partial slices into slice 0 ----------------
// grid: SLICE/256 = 1040 blocks. Each thread owns one output address.
__global__ __launch_bounds__(256) void reduce_kernel(float* __restrict__ ws, int CH)
{
    const int idx = blockIdx.x * 256 + threadIdx.x;
    float s = 0.f;
    for (int c = 0; c < CH; ++c) s += ws[(size_t)c * SLICE + idx];
    ws[idx] = s;
}

// ---------------- Pass 2: out = z * (fm(Q) @ KV) ----------------
// grid: (128 l-chunks of 64 rows, 64 nh), block: 256
__global__ __launch_bounds__(256) void out_kernel(
    const float* __restrict__ Q, const float* __restrict__ KVg,
    float* __restrict__ out)
{
    const int t      = threadIdx.x;
    const int lchunk = blockIdx.x;
    const int nh     = blockIdx.y;
    const int n = nh >> 4, h = nh & 15;

    __shared__ float Ql[64 * QSTRIDE];
    __shared__ float KVl[4096];
    __shared__ float Ks[64];
    __shared__ float zl[64];

    const float* kvrow = KVg + (size_t)nh * KV_STRIDE;

    // phase A: stage KV (16KB) + Ksum into LDS
#pragma unroll
    for (int j = 0; j < 4; ++j) {
        reinterpret_cast<float4*>(KVl)[t + 256 * j] =
            reinterpret_cast<const float4*>(kvrow)[t + 256 * j];
    }
    if (t < 16) {
        reinterpret_cast<float4*>(Ks)[t] =
            reinterpret_cast<const float4*>(kvrow + 4096)[t];
    }
    __syncthreads();

    // phase B: stage 64 Q rows (feature-mapped) + compute z per row
    const int lane16 = t & 15, grp = t >> 4;
    const int dq = lane16 << 2;
    const float4 ks4 = *reinterpret_cast<const float4*>(&Ks[dq]);
    const int qbase = (n * L_SEQ + lchunk * 64) * ROWSTRIDE + h * 64;
#pragma unroll
    for (int p = 0; p < 4; ++p) {
        const int rr = p * 16 + grp;
        const float4 qg = *reinterpret_cast<const float4*>(Q + qbase + rr * ROWSTRIDE + dq);
        float4 qf;
        qf.x = fm(qg.x); qf.y = fm(qg.y); qf.z = fm(qg.z); qf.w = fm(qg.w);
        *reinterpret_cast<float4*>(&Ql[rr * QSTRIDE + dq]) = qf;
        float dp = qf.x * ks4.x + qf.y * ks4.y + qf.z * ks4.z + qf.w * ks4.w;
        dp += __shfl_xor(dp, 1);
        dp += __shfl_xor(dp, 2);
        dp += __shfl_xor(dp, 4);
        dp += __shfl_xor(dp, 8);
        if (lane16 == 0) zl[rr] = 1.0f / dp + EPSV;
    }
    __syncthreads();

    // phase C: 64x64x64 register-tiled GEMM, 4x4 tile per thread
    const int r0 = grp << 2;
    const int c0 = lane16 << 2;
    float acc[4][4] = {};
#pragma unroll 2
    for (int d = 0; d < 64; d += 4) {
        const float4 b0 = *reinterpret_cast<const float4*>(&KVl[(d + 0) * 64 + c0]);
        const float4 b1 = *reinterpret_cast<const float4*>(&KVl[(d + 1) * 64 + c0]);
        const float4 b2 = *reinterpret_cast<const float4*>(&KVl[(d + 2) * 64 + c0]);
        const float4 b3 = *reinterpret_cast<const float4*>(&KVl[(d + 3) * 64 + c0]);
#define DO_ROW(i) do {                                                              \
        const float4 q = *reinterpret_cast<const float4*>(&Ql[(r0 + (i)) * QSTRIDE + d]); \
        acc[i][0] += q.x * b0.x + q.y * b1.x + q.z * b2.x + q.w * b3.x;             \
        acc[i][1] += q.x * b0.y + q.y * b1.y + q.z * b2.y + q.w * b3.y;             \
        acc[i][2] += q.x * b0.z + q.y * b1.z + q.z * b2.z + q.w * b3.z;             \
        acc[i][3] += q.x * b0.w + q.y * b1.w + q.z * b2.w + q.w * b3.w;             \
    } while (0)
        DO_ROW(0); DO_ROW(1); DO_ROW(2); DO_ROW(3);
#undef DO_ROW
    }

    // epilogue: scale by z, coalesced float4 stores
    const int obase = qbase;
#pragma unroll
    for (int i = 0; i < 4; ++i) {
        const float z = zl[r0 + i];
        float4 o;
        o.x = acc[i][0] * z; o.y = acc[i][1] * z; o.z = acc[i][2] * z; o.w = acc[i][3] * z;
        *reinterpret_cast<float4*>(out + obase + (r0 + i) * ROWSTRIDE + c0) = o;
    }
}

extern "C" void kernel_launch(void* const* d_in, const int* in_sizes, int n_in,
                              void* d_out, int out_size, void* d_ws, size_t ws_size,
                              hipStream_t stream) {
    const float* Q = (const float*)d_in[0];
    const float* K = (const float*)d_in[1];
    const float* V = (const float*)d_in[2];
    float* out = (float*)d_out;
    float* ws  = (float*)d_ws;

    const size_t per_slice = (size_t)SLICE * sizeof(float);   // ~1.06 MB
    size_t max_ch = ws_size / per_slice;
    int CH = max_ch >= 32 ? 32 : (max_ch >= 16 ? 16 : (max_ch >= 8 ? 8 : 0));

    if (CH > 0) {
        // deterministic split-K: partials + reduce
        const int tiles = (L_SEQ / 32) / CH;    // 256/CH
        kv_reduce_kernel<<<dim3(NH_TOT, CH), 256, 0, stream>>>(K, V, ws, tiles, 1);
        reduce_kernel<<<SLICE / 256, 256, 0, stream>>>(ws, CH);
    } else {
        // atomic fallback (tiny ws)
        hipMemsetAsync(d_ws, 0, per_slice, stream);
        kv_reduce_kernel<<<dim3(NH_TOT, 16), 256, 0, stream>>>(K, V, ws, 16, 0);
    }
    out_kernel<<<dim3(L_SEQ / 64, NH_TOT), 256, 0, stream>>>(Q, ws, out);
}